// Round 13
// baseline (156.752 us; speedup 1.0000x reference)
//
#include <hip/hip_runtime.h>
#include <math.h>

#define TOKS 16384
#define CDIM 128
#define NH 4
#define HD 32
#define HID 512
#define QSCALE 0.17677669529663687f
#define LEPS 1e-5f

typedef const float* fp;
typedef const unsigned short* bfp16;
typedef __attribute__((ext_vector_type(8))) short bf16x8;
typedef __attribute__((ext_vector_type(4))) float f32x4;

__device__ inline unsigned int bfp2(float a, float b) {
    unsigned int ua = __float_as_uint(a); ua = (ua + 0x7FFFu + ((ua >> 16) & 1u)) >> 16;
    unsigned int ub = __float_as_uint(b); ub = (ub + 0x7FFFu + ((ub >> 16) & 1u)) >> 16;
    return ua | (ub << 16);
}
__device__ inline unsigned short bf1(float a) {
    unsigned int u = __float_as_uint(a);
    return (unsigned short)((u + 0x7FFFu + ((u >> 16) & 1u)) >> 16);
}
__device__ inline float lo16(unsigned int u) { return __uint_as_float(u << 16); }
__device__ inline float hi16(unsigned int u) { return __uint_as_float(u & 0xFFFF0000u); }

// ---------------- prep: weight convert+transpose (blocks 0..767) + LN1 (blocks 768+) ----
__global__ __launch_bounds__(256) void prep(fp qw, fp pw, fp f1w, fp f2w,
                                            fp x, fp g, fp b,
                                            unsigned short* __restrict__ wt,
                                            unsigned short* __restrict__ xn) {
    const int bid = blockIdx.x;
    if (bid < 768) {
        int e = bid * 256 + threadIdx.x;
        float v;
        if (e < 49152)       { int n = e >> 7,  k = e & 127;          v = qw[(size_t)k * 384 + n]; }
        else if (e < 65536)  { int i = e - 49152;  int n = i >> 7, k = i & 127; v = pw[(size_t)k * 128 + n]; }
        else if (e < 131072) { int i = e - 65536;  int n = i >> 7, k = i & 127; v = f1w[(size_t)k * 512 + n]; }
        else                 { int i = e - 131072; int n = i >> 9, k = i & 511; v = f2w[(size_t)k * 128 + n]; }
        wt[e] = bf1(v);
    } else {
        const int t = threadIdx.x;
        const int row = (bid - 768) * 8 + (t >> 5);
        const int l = t & 31;
        const float4 v = *(const float4*)(x + (size_t)row * CDIM + l * 4);
        float s = v.x + v.y + v.z + v.w;
        float q = v.x * v.x + v.y * v.y + v.z * v.z + v.w * v.w;
#pragma unroll
        for (int m = 16; m >= 1; m >>= 1) { s += __shfl_xor(s, m); q += __shfl_xor(q, m); }
        float mu = s * (1.f / 128.f);
        float rs = rsqrtf(q * (1.f / 128.f) - mu * mu + LEPS);
        const float4 gv = *(const float4*)(g + l * 4);
        const float4 bv = *(const float4*)(b + l * 4);
        float a0 = (v.x - mu) * rs * gv.x + bv.x, a1 = (v.y - mu) * rs * gv.y + bv.y;
        float a2 = (v.z - mu) * rs * gv.z + bv.z, a3 = (v.w - mu) * rs * gv.w + bv.w;
        uint2 o; o.x = bfp2(a0, a1); o.y = bfp2(a2, a3);
        *(uint2*)(xn + (size_t)row * CDIM + l * 4) = o;
    }
}

// ---------------- k1: QKV GEMM (A=xn, 128x64 tile, K=128, N=384); Q->f32, K/V->bf16 ------
__global__ __launch_bounds__(256) void k1_mfma(bfp16 xn, bfp16 wt0, fp wb,
                                               float* __restrict__ qb,
                                               unsigned short* __restrict__ kvb) {
    __shared__ unsigned int lds[12288];
    const int m0 = blockIdx.x * 128;
    const int nb = blockIdx.y * 64;
    const int tid = threadIdx.x;
#pragma unroll
    for (int i = 0; i < 8; i++) {
        int slot = tid + i * 256;
        int m = slot >> 4, c16 = slot & 15;
        const uint4 v4 = *(const uint4*)(xn + (size_t)(m0 + m) * CDIM + c16 * 8);
        *(uint4*)&lds[m * 64 + (c16 ^ (m & 15)) * 4] = v4;
    }
#pragma unroll
    for (int i = 0; i < 4; i++) {
        int slot = tid + i * 256;
        int n = slot >> 4, c16 = slot & 15;
        const uint4 v4 = *(const uint4*)(wt0 + (size_t)(nb + n) * 128 + c16 * 8);
        *(uint4*)&lds[8192 + n * 64 + (c16 ^ (n & 15)) * 4] = v4;
    }
    __syncthreads();

    const int lane = tid & 63, wid = tid >> 6, quad = lane >> 4, l16 = lane & 15;
    f32x4 acc[2][4];
#pragma unroll
    for (int mt = 0; mt < 2; mt++)
#pragma unroll
        for (int nt = 0; nt < 4; nt++) acc[mt][nt] = (f32x4){0.f, 0.f, 0.f, 0.f};
#pragma unroll
    for (int kk = 0; kk < 4; kk++) {
        int c = kk * 4 + quad;
        bf16x8 a0 = *(bf16x8*)&lds[(wid * 32 + l16) * 64 + (c ^ l16) * 4];
        bf16x8 a1 = *(bf16x8*)&lds[(wid * 32 + 16 + l16) * 64 + (c ^ l16) * 4];
#pragma unroll
        for (int nt = 0; nt < 4; nt++) {
            bf16x8 bf = *(bf16x8*)&lds[8192 + (nt * 16 + l16) * 64 + (c ^ l16) * 4];
            acc[0][nt] = __builtin_amdgcn_mfma_f32_16x16x32_bf16(a0, bf, acc[0][nt], 0, 0, 0);
            acc[1][nt] = __builtin_amdgcn_mfma_f32_16x16x32_bf16(a1, bf, acc[1][nt], 0, 0, 0);
        }
    }
#pragma unroll
    for (int nt = 0; nt < 4; nt++) {
        int col = nb + nt * 16 + l16;
        float bias = wb[col];
#pragma unroll
        for (int mt = 0; mt < 2; mt++)
#pragma unroll
            for (int r = 0; r < 4; r++) {
                int row = m0 + wid * 32 + mt * 16 + quad * 4 + r;
                float vres = acc[mt][nt][r] + bias;
                if (col < 128)
                    qb[(size_t)row * 128 + col] = vres * QSCALE;
                else if (col < 256)
                    kvb[(size_t)row * 256 + (col - 128)] = bf1(vres);
                else
                    kvb[(size_t)row * 256 + 128 + (col - 256)] = bf1(vres);
            }
    }
}

// ---------------- k2: LDS-halo neighborhood attention (unchanged from R12) ----------------
__global__ __launch_bounds__(256) void k2_attn(const float* __restrict__ qb,
                                               const unsigned short* __restrict__ kvb,
                                               fp rpb, unsigned short* __restrict__ attnb) {
    __shared__ unsigned int ldsu[64 * 68];
    const int tile = blockIdx.x;
    const int bb = blockIdx.y;
    const int ty0 = (tile >> 5) * 2, tx0 = (tile & 31) * 2;
    const int ky0 = min(max(ty0 - 3, 0), 56);
    const int kx0 = min(max(tx0 - 3, 0), 56);
    const int tid = threadIdx.x;

#pragma unroll
    for (int i = 0; i < 4; i++) {
        int slot = tid + i * 256;
        int p = slot >> 4, c16 = slot & 15;
        int gr = (bb << 12) + (ky0 + (p >> 3)) * 64 + kx0 + (p & 7);
        const uint4 v4 = *(const uint4*)(kvb + (size_t)gr * 256 + c16 * 8);
        *(uint4*)&ldsu[p * 68 + c16 * 4] = v4;
    }

    const int u = tid >> 4;
    const int tl = u >> 2, head = u & 3;
    const int lane16 = tid & 15;
    const int d = lane16 & 3, g = lane16 >> 2;
    const int qy = ty0 + (tl >> 1), qx = tx0 + (tl & 1);
    const int token = (bb << 12) + qy * 64 + qx;

    float q[8];
    {
        const float4* qp = (const float4*)(qb + (size_t)token * 128 + head * HD + d * 8);
        float4 q0 = qp[0], q1 = qp[1];
        q[0] = q0.x; q[1] = q0.y; q[2] = q0.z; q[3] = q0.w;
        q[4] = q1.x; q[5] = q1.y; q[6] = q1.z; q[7] = q1.w;
    }
    const int gsy = min(max(qy - 3, 0), 57), gsx = min(max(qx - 3, 0), 57);
    const int ly = gsy - ky0, lx = gsx - kx0;
    const float* rp = rpb + head * 169 + (gsy - qy + 6) * 13 + (gsx - qx + 6);
    const int dwoff = head * 16 + d * 4;
    __syncthreads();

    float sc[13];
#pragma unroll
    for (int i = 0; i < 13; i++) {
        int n = g * 13 + i;
        bool ok = n < 49;
        int nn = ok ? n : 48;
        int dy = nn / 7, dx = nn - dy * 7;
        int p = (ly + dy) * 8 + (lx + dx);
        const uint4 kk = *(const uint4*)&ldsu[p * 68 + dwoff];
        float s = q[0] * lo16(kk.x) + q[1] * hi16(kk.x)
                + q[2] * lo16(kk.y) + q[3] * hi16(kk.y)
                + q[4] * lo16(kk.z) + q[5] * hi16(kk.z)
                + q[6] * lo16(kk.w) + q[7] * hi16(kk.w);
        s += __shfl_xor(s, 1);
        s += __shfl_xor(s, 2);
        sc[i] = ok ? (s + rp[dy * 13 + dx]) : -1e30f;
    }
    __syncthreads();

#pragma unroll
    for (int i = 0; i < 4; i++) {
        int slot = tid + i * 256;
        int p = slot >> 4, c16 = slot & 15;
        int gr = (bb << 12) + (ky0 + (p >> 3)) * 64 + kx0 + (p & 7);
        const uint4 v4 = *(const uint4*)(kvb + (size_t)gr * 256 + 128 + c16 * 8);
        *(uint4*)&ldsu[p * 68 + c16 * 4] = v4;
    }
    float mx = sc[0];
#pragma unroll
    for (int l = 1; l < 13; l++) mx = fmaxf(mx, sc[l]);
    mx = fmaxf(mx, __shfl_xor(mx, 4));
    mx = fmaxf(mx, __shfl_xor(mx, 8));
    float sum = 0.f;
#pragma unroll
    for (int l = 0; l < 13; l++) { sc[l] = __expf(sc[l] - mx); sum += sc[l]; }
    sum += __shfl_xor(sum, 4);
    sum += __shfl_xor(sum, 8);
    float inv = 1.f / sum;
    __syncthreads();

    float o[8];
#pragma unroll
    for (int i = 0; i < 8; i++) o[i] = 0.f;
#pragma unroll
    for (int i = 0; i < 13; i++) {
        int n = g * 13 + i;
        int nn = (n < 49) ? n : 48;
        int dy = nn / 7, dx = nn - dy * 7;
        int p = (ly + dy) * 8 + (lx + dx);
        float pr = sc[i] * inv;
        const uint4 vv = *(const uint4*)&ldsu[p * 68 + dwoff];
        o[0] += pr * lo16(vv.x); o[1] += pr * hi16(vv.x);
        o[2] += pr * lo16(vv.y); o[3] += pr * hi16(vv.y);
        o[4] += pr * lo16(vv.z); o[5] += pr * hi16(vv.z);
        o[6] += pr * lo16(vv.w); o[7] += pr * hi16(vv.w);
    }
#pragma unroll
    for (int i = 0; i < 8; i++) {
        o[i] += __shfl_xor(o[i], 4);
        o[i] += __shfl_xor(o[i], 8);
    }
    if (g == 0) {
        uint4 ov;
        ov.x = bfp2(o[0], o[1]); ov.y = bfp2(o[2], o[3]);
        ov.z = bfp2(o[4], o[5]); ov.w = bfp2(o[6], o[7]);
        *(uint4*)(attnb + (size_t)token * 128 + head * HD + d * 8) = ov;
    }
}

// ---------------- k345: proj + residual + LN2 + fc1 + GELU + fc2 + residual -> out -------
// Block = 64 rows, 256 thr. LDS 64KB: A/hn @0 (16K), B-stage @4096 (32K), Y @12288 (16K).
// h stays in registers (proj and fc2 use identical M x N tiling).
__global__ __launch_bounds__(256) void k345(bfp16 attnb, fp x, bfp16 wt1, fp pb,
                                            fp g2, fp b2, bfp16 wt2, fp f1b,
                                            bfp16 wt3, fp f2b, float* __restrict__ out) {
    __shared__ unsigned int lds[16384];
    unsigned short* ldsh = (unsigned short*)lds;
    const int m0 = blockIdx.x * 64;
    const int tid = threadIdx.x;
    const int lane = tid & 63, wid = tid >> 6, quad = lane >> 4, l16 = lane & 15;
    const int mrow = wid * 16 + l16;

    // ---- phase 1: stage attnb -> A, wt1 -> B
#pragma unroll
    for (int i = 0; i < 4; i++) {
        int slot = tid + i * 256;
        int m = slot >> 4, c16 = slot & 15;
        const uint4 v4 = *(const uint4*)(attnb + (size_t)(m0 + m) * CDIM + c16 * 8);
        *(uint4*)&lds[m * 64 + (c16 ^ (m & 15)) * 4] = v4;
    }
#pragma unroll
    for (int i = 0; i < 8; i++) {
        int slot = tid + i * 256;
        int n = slot >> 4, c16 = slot & 15;
        const uint4 v4 = *(const uint4*)(wt1 + (size_t)n * 128 + c16 * 8);
        *(uint4*)&lds[4096 + n * 64 + (c16 ^ (n & 15)) * 4] = v4;
    }
    __syncthreads();

    // ---- phase 2: proj GEMM (M64 N128 K128)
    f32x4 hacc[8];
#pragma unroll
    for (int nt = 0; nt < 8; nt++) hacc[nt] = (f32x4){0.f, 0.f, 0.f, 0.f};
#pragma unroll
    for (int kk = 0; kk < 4; kk++) {
        int c = kk * 4 + quad;
        bf16x8 a = *(bf16x8*)&lds[mrow * 64 + (c ^ l16) * 4];
#pragma unroll
        for (int nt = 0; nt < 8; nt++) {
            bf16x8 bf = *(bf16x8*)&lds[4096 + (nt * 16 + l16) * 64 + (c ^ l16) * 4];
            hacc[nt] = __builtin_amdgcn_mfma_f32_16x16x32_bf16(a, bf, hacc[nt], 0, 0, 0);
        }
    }
    __syncthreads();   // A reads done before hn overwrite

    // ---- phase 3: residual + LN2 stats + hn -> A (bf16)
    float s[4] = {0.f, 0.f, 0.f, 0.f}, q[4] = {0.f, 0.f, 0.f, 0.f};
#pragma unroll
    for (int nt = 0; nt < 8; nt++) {
        int col = nt * 16 + l16;
        float bias = pb[col];
#pragma unroll
        for (int r = 0; r < 4; r++) {
            int row = m0 + wid * 16 + quad * 4 + r;
            float hv = x[(size_t)row * CDIM + col] + hacc[nt][r] + bias;
            hacc[nt][r] = hv;           // h lives here until the very end
            s[r] += hv; q[r] += hv * hv;
        }
    }
#pragma unroll
    for (int m = 1; m <= 8; m <<= 1) {
#pragma unroll
        for (int r = 0; r < 4; r++) {
            s[r] += __shfl_xor(s[r], m);
            q[r] += __shfl_xor(q[r], m);
        }
    }
    float mu[4], rs[4];
#pragma unroll
    for (int r = 0; r < 4; r++) {
        mu[r] = s[r] * (1.f / 128.f);
        rs[r] = rsqrtf(q[r] * (1.f / 128.f) - mu[r] * mu[r] + LEPS);
    }
#pragma unroll
    for (int nt = 0; nt < 8; nt++) {
        int col = nt * 16 + l16;
        float gg = g2[col], bb = b2[col];
#pragma unroll
        for (int r = 0; r < 4; r++) {
            int m = wid * 16 + quad * 4 + r;
            unsigned short hb = bf1((hacc[nt][r] - mu[r]) * rs[r] * gg + bb);
            int dw = m * 64 + (((col >> 3) ^ (m & 15)) << 2) + ((col >> 1) & 3);
            ldsh[dw * 2 + (col & 1)] = hb;
        }
    }

    // ---- phase 4/5: fc1+gelu+fc2 in 4 chunks of 128 hidden cols
    f32x4 accF[8];
#pragma unroll
    for (int nt = 0; nt < 8; nt++) accF[nt] = (f32x4){0.f, 0.f, 0.f, 0.f};

    for (int nc = 0; nc < 4; nc++) {
        __syncthreads();   // hn/Y/B consumers done
        // stage wt2 chunk [128n][128k] -> B
#pragma unroll
        for (int i = 0; i < 8; i++) {
            int slot = tid + i * 256;
            int n = slot >> 4, c16 = slot & 15;
            const uint4 v4 = *(const uint4*)(wt2 + (size_t)(nc * 128 + n) * 128 + c16 * 8);
            *(uint4*)&lds[4096 + n * 64 + (c16 ^ (n & 15)) * 4] = v4;
        }
        __syncthreads();
        // fc1 (A=hn, B=wt2 chunk) + gelu -> Y
        f32x4 acc2[8];
#pragma unroll
        for (int nt = 0; nt < 8; nt++) acc2[nt] = (f32x4){0.f, 0.f, 0.f, 0.f};
#pragma unroll
        for (int kk = 0; kk < 4; kk++) {
            int c = kk * 4 + quad;
            bf16x8 a = *(bf16x8*)&lds[mrow * 64 + (c ^ l16) * 4];
#pragma unroll
            for (int nt = 0; nt < 8; nt++) {
                bf16x8 bf = *(bf16x8*)&lds[4096 + (nt * 16 + l16) * 64 + (c ^ l16) * 4];
                acc2[nt] = __builtin_amdgcn_mfma_f32_16x16x32_bf16(a, bf, acc2[nt], 0, 0, 0);
            }
        }
#pragma unroll
        for (int nt = 0; nt < 8; nt++) {
            int k = nt * 16 + l16;             // local hidden col 0..127
            float bias = f1b[nc * 128 + k];
#pragma unroll
            for (int r = 0; r < 4; r++) {
                int m = wid * 16 + quad * 4 + r;
                float z = acc2[nt][r] + bias;
                float ge = 0.5f * z * (1.f + erff(z * 0.70710678118654752f));
                int dw = 12288 + m * 64 + (((k >> 3) ^ (m & 15)) << 2) + ((k >> 1) & 3);
                ldsh[dw * 2 + (k & 1)] = bf1(ge);
            }
        }
        __syncthreads();   // Y complete, B reads done
        // stage wt3 chunk [128n][k-chunk 128] -> B
#pragma unroll
        for (int i = 0; i < 8; i++) {
            int slot = tid + i * 256;
            int n = slot >> 4, c16 = slot & 15;
            const uint4 v4 = *(const uint4*)(wt3 + (size_t)n * 512 + nc * 128 + c16 * 8);
            *(uint4*)&lds[4096 + n * 64 + (c16 ^ (n & 15)) * 4] = v4;
        }
        __syncthreads();
        // fc2 partial (A=Y, B=wt3 chunk)
#pragma unroll
        for (int kk = 0; kk < 4; kk++) {
            int c = kk * 4 + quad;
            bf16x8 a = *(bf16x8*)&lds[12288 + mrow * 64 + (c ^ l16) * 4];
#pragma unroll
            for (int nt = 0; nt < 8; nt++) {
                bf16x8 bf = *(bf16x8*)&lds[4096 + (nt * 16 + l16) * 64 + (c ^ l16) * 4];
                accF[nt] = __builtin_amdgcn_mfma_f32_16x16x32_bf16(a, bf, accF[nt], 0, 0, 0);
            }
        }
    }

    // ---- phase 6: out = h + fc2 + bias
#pragma unroll
    for (int nt = 0; nt < 8; nt++) {
        int col = nt * 16 + l16;
        float bias = f2b[col];
#pragma unroll
        for (int r = 0; r < 4; r++) {
            int row = m0 + wid * 16 + quad * 4 + r;
            out[(size_t)row * CDIM + col] = hacc[nt][r] + accF[nt][r] + bias;
        }
    }
}

extern "C" void kernel_launch(void* const* d_in, const int* in_sizes, int n_in,
                              void* d_out, int out_size, void* d_ws, size_t ws_size,
                              hipStream_t stream) {
    fp x      = (fp)d_in[0];
    fp ln1_g  = (fp)d_in[1];
    fp ln1_b  = (fp)d_in[2];
    fp qkv_w  = (fp)d_in[3];
    fp qkv_b  = (fp)d_in[4];
    fp rpb    = (fp)d_in[5];
    fp proj_w = (fp)d_in[6];
    fp proj_b = (fp)d_in[7];
    fp ln2_g  = (fp)d_in[8];
    fp ln2_b  = (fp)d_in[9];
    fp fc1_w  = (fp)d_in[10];
    fp fc1_b  = (fp)d_in[11];
    fp fc2_w  = (fp)d_in[12];
    fp fc2_b  = (fp)d_in[13];
    float* out = (float*)d_out;

    // workspace: xn bf16[TOKS*128] | qb f32[TOKS*128] | kvb bf16[TOKS*256]
    //            | attnb bf16[TOKS*128] | wt bf16[196608]
    unsigned short* xn = (unsigned short*)d_ws;
    float* qb = (float*)(xn + (size_t)TOKS * CDIM);
    unsigned short* kvb   = (unsigned short*)(qb + (size_t)TOKS * CDIM);
    unsigned short* attnb = kvb + (size_t)TOKS * 256;
    unsigned short* wt    = attnb + (size_t)TOKS * CDIM;

    unsigned short* wt0 = wt;            // qkv  [384][128]
    unsigned short* wt1 = wt + 49152;    // proj [128][128]
    unsigned short* wt2 = wt + 65536;    // fc1  [512][128]
    unsigned short* wt3 = wt + 131072;   // fc2  [128][512]

    prep<<<768 + TOKS / 8, 256, 0, stream>>>(qkv_w, proj_w, fc1_w, fc2_w, x, ln1_g, ln1_b, wt, xn);
    k1_mfma<<<dim3(TOKS / 128, 6), 256, 0, stream>>>(xn, wt0, qkv_b, qb, kvb);
    k2_attn<<<dim3(1024, 4), 256, 0, stream>>>(qb, kvb, rpb, attnb);
    k345<<<TOKS / 64, 256, 0, stream>>>(attnb, x, wt1, proj_b, ln2_g, ln2_b,
                                        wt2, fc1_b, wt3, fc2_b, out);
}

// Round 14
// 155.822 us; speedup vs baseline: 1.0060x; 1.0060x over previous
//
#include <hip/hip_runtime.h>
#include <math.h>

#define TOKS 16384
#define CDIM 128
#define NH 4
#define HD 32
#define HID 512
#define QSCALE 0.17677669529663687f
#define LEPS 1e-5f

typedef const float* fp;
typedef const unsigned short* bfp16;
typedef __attribute__((ext_vector_type(8))) short bf16x8;
typedef __attribute__((ext_vector_type(4))) float f32x4;

__device__ inline unsigned int bfp2(float a, float b) {
    unsigned int ua = __float_as_uint(a); ua = (ua + 0x7FFFu + ((ua >> 16) & 1u)) >> 16;
    unsigned int ub = __float_as_uint(b); ub = (ub + 0x7FFFu + ((ub >> 16) & 1u)) >> 16;
    return ua | (ub << 16);
}
__device__ inline unsigned short bf1(float a) {
    unsigned int u = __float_as_uint(a);
    return (unsigned short)((u + 0x7FFFu + ((u >> 16) & 1u)) >> 16);
}
__device__ inline float lo16(unsigned int u) { return __uint_as_float(u << 16); }
__device__ inline float hi16(unsigned int u) { return __uint_as_float(u & 0xFFFF0000u); }

// ---------------- prep: weight convert+transpose (blocks 0..767) + LN1 (blocks 768+) ----
__global__ __launch_bounds__(256) void prep(fp qw, fp pw, fp f1w, fp f2w,
                                            fp x, fp g, fp b,
                                            unsigned short* __restrict__ wt,
                                            unsigned short* __restrict__ xn) {
    const int bid = blockIdx.x;
    if (bid < 768) {
        int e = bid * 256 + threadIdx.x;
        float v;
        if (e < 49152)       { int n = e >> 7,  k = e & 127;          v = qw[(size_t)k * 384 + n]; }
        else if (e < 65536)  { int i = e - 49152;  int n = i >> 7, k = i & 127; v = pw[(size_t)k * 128 + n]; }
        else if (e < 131072) { int i = e - 65536;  int n = i >> 7, k = i & 127; v = f1w[(size_t)k * 512 + n]; }
        else                 { int i = e - 131072; int n = i >> 9, k = i & 511; v = f2w[(size_t)k * 128 + n]; }
        wt[e] = bf1(v);
    } else {
        const int t = threadIdx.x;
        const int row = (bid - 768) * 8 + (t >> 5);
        const int l = t & 31;
        const float4 v = *(const float4*)(x + (size_t)row * CDIM + l * 4);
        float s = v.x + v.y + v.z + v.w;
        float q = v.x * v.x + v.y * v.y + v.z * v.z + v.w * v.w;
#pragma unroll
        for (int m = 16; m >= 1; m >>= 1) { s += __shfl_xor(s, m); q += __shfl_xor(q, m); }
        float mu = s * (1.f / 128.f);
        float rs = rsqrtf(q * (1.f / 128.f) - mu * mu + LEPS);
        const float4 gv = *(const float4*)(g + l * 4);
        const float4 bv = *(const float4*)(b + l * 4);
        float a0 = (v.x - mu) * rs * gv.x + bv.x, a1 = (v.y - mu) * rs * gv.y + bv.y;
        float a2 = (v.z - mu) * rs * gv.z + bv.z, a3 = (v.w - mu) * rs * gv.w + bv.w;
        uint2 o; o.x = bfp2(a0, a1); o.y = bfp2(a2, a3);
        *(uint2*)(xn + (size_t)row * CDIM + l * 4) = o;
    }
}

// ================= MFMA GEMM kernels =================
// k1/k4/k5 tile: 128(M) x 64(N), 256 threads = 4 waves; wave = 32 rows x 4 n-tiles.
// 1D grids, XCD-swizzled: xcd = bid&7 owns 16 consecutive m-slices (A L2-resident per XCD).

// ---------------- k1: QKV GEMM (A=xn, K=128, N=384) -> qkvb bf16 (q pre-scaled) ---------
__global__ __launch_bounds__(256) void k1_mfma(bfp16 xn, bfp16 wt0, fp wb,
                                               unsigned short* __restrict__ qkvb) {
    __shared__ unsigned int lds[12288];
    const int bid = blockIdx.x;                 // 768
    const int xcd = bid & 7, idx = bid >> 3;    // idx 0..95
    const int m0 = (xcd * 16 + (idx & 15)) * 128;
    const int nb = (idx >> 4) * 64;             // 0..5
    const int tid = threadIdx.x;
#pragma unroll
    for (int i = 0; i < 8; i++) {
        int slot = tid + i * 256;
        int m = slot >> 4, c16 = slot & 15;
        const uint4 v4 = *(const uint4*)(xn + (size_t)(m0 + m) * CDIM + c16 * 8);
        *(uint4*)&lds[m * 64 + (c16 ^ (m & 15)) * 4] = v4;
    }
#pragma unroll
    for (int i = 0; i < 4; i++) {
        int slot = tid + i * 256;
        int n = slot >> 4, c16 = slot & 15;
        const uint4 v4 = *(const uint4*)(wt0 + (size_t)(nb + n) * 128 + c16 * 8);
        *(uint4*)&lds[8192 + n * 64 + (c16 ^ (n & 15)) * 4] = v4;
    }
    __syncthreads();

    const int lane = tid & 63, wid = tid >> 6, quad = lane >> 4, l16 = lane & 15;
    f32x4 acc[2][4];
#pragma unroll
    for (int mt = 0; mt < 2; mt++)
#pragma unroll
        for (int nt = 0; nt < 4; nt++) acc[mt][nt] = (f32x4){0.f, 0.f, 0.f, 0.f};
#pragma unroll
    for (int kk = 0; kk < 4; kk++) {
        int c = kk * 4 + quad;
        bf16x8 a0 = *(bf16x8*)&lds[(wid * 32 + l16) * 64 + (c ^ l16) * 4];
        bf16x8 a1 = *(bf16x8*)&lds[(wid * 32 + 16 + l16) * 64 + (c ^ l16) * 4];
#pragma unroll
        for (int nt = 0; nt < 4; nt++) {
            bf16x8 bf = *(bf16x8*)&lds[8192 + (nt * 16 + l16) * 64 + (c ^ l16) * 4];
            acc[0][nt] = __builtin_amdgcn_mfma_f32_16x16x32_bf16(a0, bf, acc[0][nt], 0, 0, 0);
            acc[1][nt] = __builtin_amdgcn_mfma_f32_16x16x32_bf16(a1, bf, acc[1][nt], 0, 0, 0);
        }
    }
#pragma unroll
    for (int nt = 0; nt < 4; nt++) {
        int col = nb + nt * 16 + l16;
        float bias = wb[col];
        float sc = (col < 128) ? QSCALE : 1.f;
#pragma unroll
        for (int mt = 0; mt < 2; mt++)
#pragma unroll
            for (int r = 0; r < 4; r++) {
                int row = m0 + wid * 32 + mt * 16 + quad * 4 + r;
                qkvb[(size_t)row * 384 + col] = bf1((acc[mt][nt][r] + bias) * sc);
            }
    }
}

// ---------------- k2: neighborhood attention, 16 lanes per (token, head), all-bf16 ------
// XCD swizzle: xcd = bid&7 owns a contiguous 2048-token band (KV footprint ~1.2 MB/XCD).
__global__ __launch_bounds__(256) void k2_attn(bfp16 qkvb, fp rpb,
                                               unsigned short* __restrict__ attnb) {
    const int bid = blockIdx.x;                 // 4096
    const int xcd = bid & 7, idx = bid >> 3;    // idx 0..511
    const int token = xcd * 2048 + idx * 4 + (threadIdx.x >> 6);
    const int lane = threadIdx.x & 63;
    const int d = lane & 3;
    const int g = (lane >> 2) & 3;
    const int head = lane >> 4;
    const int bb = token >> 12;
    const int y = (token >> 6) & 63;
    const int xx = token & 63;
    const int sy = min(max(y - 3, 0), 57);
    const int sx = min(max(xx - 3, 0), 57);

    const int koff = head * HD + d * 8;
    float q[8];
    {
        const uint4 qv = *(const uint4*)(qkvb + (size_t)token * 384 + koff);
        q[0] = lo16(qv.x); q[1] = hi16(qv.x); q[2] = lo16(qv.y); q[3] = hi16(qv.y);
        q[4] = lo16(qv.z); q[5] = hi16(qv.z); q[6] = lo16(qv.w); q[7] = hi16(qv.w);
    }

    const float* rp = rpb + head * 169 + (sy - y + 6) * 13 + (sx - xx + 6);
    const int nbase = (bb << 12) + sy * 64 + sx;

    float sc[13];
#pragma unroll
    for (int i = 0; i < 13; i++) {
        int n = g * 13 + i;
        bool ok = n < 49;
        int nn = ok ? n : 48;
        int dy = nn / 7, dx = nn - dy * 7;
        const uint4 kk = *(const uint4*)(qkvb + (size_t)(nbase + dy * 64 + dx) * 384 + 128 + koff);
        float s = q[0] * lo16(kk.x) + q[1] * hi16(kk.x)
                + q[2] * lo16(kk.y) + q[3] * hi16(kk.y)
                + q[4] * lo16(kk.z) + q[5] * hi16(kk.z)
                + q[6] * lo16(kk.w) + q[7] * hi16(kk.w);
        s += __shfl_xor(s, 1);
        s += __shfl_xor(s, 2);
        sc[i] = ok ? (s + rp[dy * 13 + dx]) : -1e30f;
    }
    float mx = sc[0];
#pragma unroll
    for (int l = 1; l < 13; l++) mx = fmaxf(mx, sc[l]);
    mx = fmaxf(mx, __shfl_xor(mx, 4));
    mx = fmaxf(mx, __shfl_xor(mx, 8));
    float sum = 0.f;
#pragma unroll
    for (int l = 0; l < 13; l++) { sc[l] = __expf(sc[l] - mx); sum += sc[l]; }
    sum += __shfl_xor(sum, 4);
    sum += __shfl_xor(sum, 8);
    float inv = 1.f / sum;

    float o[8];
#pragma unroll
    for (int i = 0; i < 8; i++) o[i] = 0.f;
#pragma unroll
    for (int i = 0; i < 13; i++) {
        int n = g * 13 + i;
        int nn = (n < 49) ? n : 48;
        int dy = nn / 7, dx = nn - dy * 7;
        float p = sc[i] * inv;
        const uint4 vv = *(const uint4*)(qkvb + (size_t)(nbase + dy * 64 + dx) * 384 + 256 + koff);
        o[0] += p * lo16(vv.x); o[1] += p * hi16(vv.x);
        o[2] += p * lo16(vv.y); o[3] += p * hi16(vv.y);
        o[4] += p * lo16(vv.z); o[5] += p * hi16(vv.z);
        o[6] += p * lo16(vv.w); o[7] += p * hi16(vv.w);
    }
#pragma unroll
    for (int i = 0; i < 8; i++) {
        o[i] += __shfl_xor(o[i], 4);
        o[i] += __shfl_xor(o[i], 8);
    }
    if (g == 0) {
        uint4 ov;
        ov.x = bfp2(o[0], o[1]); ov.y = bfp2(o[2], o[3]);
        ov.z = bfp2(o[4], o[5]); ov.w = bfp2(o[6], o[7]);
        *(uint4*)(attnb + (size_t)token * 128 + koff) = ov;
    }
}

// ---------------- k3: proj GEMM (64x128 tile) + residual + fused LN2 -> h, hn ----------
__global__ __launch_bounds__(256) void k3_mfma(bfp16 attnb, fp x, bfp16 wt1, fp pb,
                                               fp g2, fp b2,
                                               float* __restrict__ h,
                                               unsigned short* __restrict__ hn) {
    __shared__ unsigned int lds[12288];   // A 4096 + B 8192
    const int m0 = blockIdx.x * 64;
    const int tid = threadIdx.x;
#pragma unroll
    for (int i = 0; i < 4; i++) {
        int slot = tid + i * 256;
        int m = slot >> 4, c16 = slot & 15;
        const uint4 v4 = *(const uint4*)(attnb + (size_t)(m0 + m) * CDIM + c16 * 8);
        *(uint4*)&lds[m * 64 + (c16 ^ (m & 15)) * 4] = v4;
    }
#pragma unroll
    for (int i = 0; i < 8; i++) {
        int slot = tid + i * 256;
        int n = slot >> 4, c16 = slot & 15;
        const uint4 v4 = *(const uint4*)(wt1 + (size_t)n * 128 + c16 * 8);
        *(uint4*)&lds[4096 + n * 64 + (c16 ^ (n & 15)) * 4] = v4;
    }
    __syncthreads();

    const int lane = tid & 63, wid = tid >> 6, quad = lane >> 4, l16 = lane & 15;
    const int mrow = wid * 16 + l16;
    f32x4 acc[8];
#pragma unroll
    for (int nt = 0; nt < 8; nt++) acc[nt] = (f32x4){0.f, 0.f, 0.f, 0.f};
#pragma unroll
    for (int kk = 0; kk < 4; kk++) {
        int c = kk * 4 + quad;
        bf16x8 a = *(bf16x8*)&lds[mrow * 64 + (c ^ l16) * 4];
#pragma unroll
        for (int nt = 0; nt < 8; nt++) {
            bf16x8 bf = *(bf16x8*)&lds[4096 + (nt * 16 + l16) * 64 + (c ^ l16) * 4];
            acc[nt] = __builtin_amdgcn_mfma_f32_16x16x32_bf16(a, bf, acc[nt], 0, 0, 0);
        }
    }
    float s[4] = {0.f, 0.f, 0.f, 0.f}, q[4] = {0.f, 0.f, 0.f, 0.f};
#pragma unroll
    for (int nt = 0; nt < 8; nt++) {
        int col = nt * 16 + l16;
        float bias = pb[col];
#pragma unroll
        for (int r = 0; r < 4; r++) {
            int row = m0 + wid * 16 + quad * 4 + r;
            float hv = x[(size_t)row * CDIM + col] + acc[nt][r] + bias;
            h[(size_t)row * CDIM + col] = hv;
            acc[nt][r] = hv;
            s[r] += hv; q[r] += hv * hv;
        }
    }
#pragma unroll
    for (int m = 1; m <= 8; m <<= 1) {
#pragma unroll
        for (int r = 0; r < 4; r++) {
            s[r] += __shfl_xor(s[r], m);
            q[r] += __shfl_xor(q[r], m);
        }
    }
    float mu[4], rs[4];
#pragma unroll
    for (int r = 0; r < 4; r++) {
        mu[r] = s[r] * (1.f / 128.f);
        rs[r] = rsqrtf(q[r] * (1.f / 128.f) - mu[r] * mu[r] + LEPS);
    }
#pragma unroll
    for (int nt = 0; nt < 8; nt++) {
        int col = nt * 16 + l16;
        float gg = g2[col], bb = b2[col];
#pragma unroll
        for (int r = 0; r < 4; r++) {
            int row = m0 + wid * 16 + quad * 4 + r;
            hn[(size_t)row * CDIM + col] = bf1((acc[nt][r] - mu[r]) * rs[r] * gg + bb);
        }
    }
}

// ---------------- k4: fc1 + GELU (A=hn, K=128, N=512) -> y1 bf16 ----------------
__global__ __launch_bounds__(256) void k4_mfma(bfp16 hn, bfp16 wt2, fp wb,
                                               unsigned short* __restrict__ y1) {
    __shared__ unsigned int lds[12288];
    const int bid = blockIdx.x;                 // 1024
    const int xcd = bid & 7, idx = bid >> 3;    // idx 0..127
    const int m0 = (xcd * 16 + (idx & 15)) * 128;
    const int nb = (idx >> 4) * 64;             // 0..7
    const int tid = threadIdx.x;
#pragma unroll
    for (int i = 0; i < 8; i++) {
        int slot = tid + i * 256;
        int m = slot >> 4, c16 = slot & 15;
        const uint4 v4 = *(const uint4*)(hn + (size_t)(m0 + m) * CDIM + c16 * 8);
        *(uint4*)&lds[m * 64 + (c16 ^ (m & 15)) * 4] = v4;
    }
#pragma unroll
    for (int i = 0; i < 4; i++) {
        int slot = tid + i * 256;
        int n = slot >> 4, c16 = slot & 15;
        const uint4 v4 = *(const uint4*)(wt2 + (size_t)(nb + n) * 128 + c16 * 8);
        *(uint4*)&lds[8192 + n * 64 + (c16 ^ (n & 15)) * 4] = v4;
    }
    __syncthreads();

    const int lane = tid & 63, wid = tid >> 6, quad = lane >> 4, l16 = lane & 15;
    f32x4 acc[2][4];
#pragma unroll
    for (int mt = 0; mt < 2; mt++)
#pragma unroll
        for (int nt = 0; nt < 4; nt++) acc[mt][nt] = (f32x4){0.f, 0.f, 0.f, 0.f};
#pragma unroll
    for (int kk = 0; kk < 4; kk++) {
        int c = kk * 4 + quad;
        bf16x8 a0 = *(bf16x8*)&lds[(wid * 32 + l16) * 64 + (c ^ l16) * 4];
        bf16x8 a1 = *(bf16x8*)&lds[(wid * 32 + 16 + l16) * 64 + (c ^ l16) * 4];
#pragma unroll
        for (int nt = 0; nt < 4; nt++) {
            bf16x8 bf = *(bf16x8*)&lds[8192 + (nt * 16 + l16) * 64 + (c ^ l16) * 4];
            acc[0][nt] = __builtin_amdgcn_mfma_f32_16x16x32_bf16(a0, bf, acc[0][nt], 0, 0, 0);
            acc[1][nt] = __builtin_amdgcn_mfma_f32_16x16x32_bf16(a1, bf, acc[1][nt], 0, 0, 0);
        }
    }
#pragma unroll
    for (int nt = 0; nt < 4; nt++) {
        int col = nb + nt * 16 + l16;
        float bias = wb[col];
#pragma unroll
        for (int mt = 0; mt < 2; mt++)
#pragma unroll
            for (int r = 0; r < 4; r++) {
                int row = m0 + wid * 32 + mt * 16 + quad * 4 + r;
                float z = acc[mt][nt][r] + bias;
                y1[(size_t)row * HID + col] = bf1(0.5f * z * (1.f + erff(z * 0.70710678118654752f)));
            }
    }
}

// ---------------- k5: fc2 + residual (K=512 in 4 chunks, N=128) ----------------
__global__ __launch_bounds__(256) void k5_mfma(bfp16 y1, fp h, bfp16 wt3, fp wb,
                                               float* __restrict__ out) {
    __shared__ unsigned int lds[12288];
    const int bid = blockIdx.x;                 // 256
    const int xcd = bid & 7, idx = bid >> 3;    // idx 0..31
    const int m0 = (xcd * 16 + (idx & 15)) * 128;
    const int nb = (idx >> 4) * 64;             // 0..1
    const int tid = threadIdx.x;
    const int lane = tid & 63, wid = tid >> 6, quad = lane >> 4, l16 = lane & 15;
    f32x4 acc[2][4];
#pragma unroll
    for (int mt = 0; mt < 2; mt++)
#pragma unroll
        for (int nt = 0; nt < 4; nt++) acc[mt][nt] = (f32x4){0.f, 0.f, 0.f, 0.f};

    for (int kc = 0; kc < 4; kc++) {
        if (kc) __syncthreads();
#pragma unroll
        for (int i = 0; i < 8; i++) {
            int slot = tid + i * 256;
            int m = slot >> 4, c16 = slot & 15;
            const uint4 v4 = *(const uint4*)(y1 + (size_t)(m0 + m) * HID + kc * 128 + c16 * 8);
            *(uint4*)&lds[m * 64 + (c16 ^ (m & 15)) * 4] = v4;
        }
#pragma unroll
        for (int i = 0; i < 4; i++) {
            int slot = tid + i * 256;
            int n = slot >> 4, c16 = slot & 15;
            const uint4 v4 = *(const uint4*)(wt3 + (size_t)(nb + n) * 512 + kc * 128 + c16 * 8);
            *(uint4*)&lds[8192 + n * 64 + (c16 ^ (n & 15)) * 4] = v4;
        }
        __syncthreads();
#pragma unroll
        for (int kk = 0; kk < 4; kk++) {
            int c = kk * 4 + quad;
            bf16x8 a0 = *(bf16x8*)&lds[(wid * 32 + l16) * 64 + (c ^ l16) * 4];
            bf16x8 a1 = *(bf16x8*)&lds[(wid * 32 + 16 + l16) * 64 + (c ^ l16) * 4];
#pragma unroll
            for (int nt = 0; nt < 4; nt++) {
                bf16x8 bf = *(bf16x8*)&lds[8192 + (nt * 16 + l16) * 64 + (c ^ l16) * 4];
                acc[0][nt] = __builtin_amdgcn_mfma_f32_16x16x32_bf16(a0, bf, acc[0][nt], 0, 0, 0);
                acc[1][nt] = __builtin_amdgcn_mfma_f32_16x16x32_bf16(a1, bf, acc[1][nt], 0, 0, 0);
            }
        }
    }
#pragma unroll
    for (int nt = 0; nt < 4; nt++) {
        int col = nb + nt * 16 + l16;
        float bias = wb[col];
#pragma unroll
        for (int mt = 0; mt < 2; mt++)
#pragma unroll
            for (int r = 0; r < 4; r++) {
                int row = m0 + wid * 32 + mt * 16 + quad * 4 + r;
                out[(size_t)row * CDIM + col] = h[(size_t)row * CDIM + col] + acc[mt][nt][r] + bias;
            }
    }
}

extern "C" void kernel_launch(void* const* d_in, const int* in_sizes, int n_in,
                              void* d_out, int out_size, void* d_ws, size_t ws_size,
                              hipStream_t stream) {
    fp x      = (fp)d_in[0];
    fp ln1_g  = (fp)d_in[1];
    fp ln1_b  = (fp)d_in[2];
    fp qkv_w  = (fp)d_in[3];
    fp qkv_b  = (fp)d_in[4];
    fp rpb    = (fp)d_in[5];
    fp proj_w = (fp)d_in[6];
    fp proj_b = (fp)d_in[7];
    fp ln2_g  = (fp)d_in[8];
    fp ln2_b  = (fp)d_in[9];
    fp fc1_w  = (fp)d_in[10];
    fp fc1_b  = (fp)d_in[11];
    fp fc2_w  = (fp)d_in[12];
    fp fc2_b  = (fp)d_in[13];
    float* out = (float*)d_out;

    // workspace (ushorts unless noted):
    //   qkvb  [TOKS*384]  (q|k|v bf16; q pre-scaled)   — dead after k2
    //   attnb [TOKS*128]                               — dead after k3
    //   y1    [TOKS*512]  aliases qkvb+attnb exactly   — live k4..k5
    //   xn    [TOKS*128], hn [TOKS*128], wt [196608], h f32 [TOKS*128]
    unsigned short* qkvb  = (unsigned short*)d_ws;
    unsigned short* attnb = qkvb + (size_t)TOKS * 384;
    unsigned short* y1    = qkvb;                      // TOKS*512 total
    unsigned short* xn    = qkvb + (size_t)TOKS * 512;
    unsigned short* hn    = xn + (size_t)TOKS * CDIM;
    unsigned short* wt    = hn + (size_t)TOKS * CDIM;
    float* h = (float*)(wt + 196608);

    unsigned short* wt0 = wt;            // qkv  [384][128]
    unsigned short* wt1 = wt + 49152;    // proj [128][128]
    unsigned short* wt2 = wt + 65536;    // fc1  [512][128]
    unsigned short* wt3 = wt + 131072;   // fc2  [128][512]

    prep<<<768 + TOKS / 8, 256, 0, stream>>>(qkv_w, proj_w, fc1_w, fc2_w, x, ln1_g, ln1_b, wt, xn);
    k1_mfma<<<768, 256, 0, stream>>>(xn, wt0, qkv_b, qkvb);
    k2_attn<<<4096, 256, 0, stream>>>(qkvb, rpb, attnb);
    k3_mfma<<<TOKS / 64, 256, 0, stream>>>(attnb, x, wt1, proj_b, ln2_g, ln2_b, h, hn);
    k4_mfma<<<1024, 256, 0, stream>>>(hn, wt2, fc1_b, y1);
    k5_mfma<<<256, 256, 0, stream>>>(y1, h, wt3, fc2_b, out);
}

// Round 15
// 149.676 us; speedup vs baseline: 1.0473x; 1.0411x over previous
//
#include <hip/hip_runtime.h>
#include <math.h>

#define TOKS 16384
#define CDIM 128
#define NH 4
#define HD 32
#define HID 512
#define QSCALE 0.17677669529663687f
#define LEPS 1e-5f

typedef const float* fp;
typedef const unsigned short* bfp16;
typedef __attribute__((ext_vector_type(8))) short bf16x8;
typedef __attribute__((ext_vector_type(4))) float f32x4;

__device__ inline unsigned int bfp2(float a, float b) {
    unsigned int ua = __float_as_uint(a); ua = (ua + 0x7FFFu + ((ua >> 16) & 1u)) >> 16;
    unsigned int ub = __float_as_uint(b); ub = (ub + 0x7FFFu + ((ub >> 16) & 1u)) >> 16;
    return ua | (ub << 16);
}
__device__ inline unsigned short bf1(float a) {
    unsigned int u = __float_as_uint(a);
    return (unsigned short)((u + 0x7FFFu + ((u >> 16) & 1u)) >> 16);
}
__device__ inline float lo16(unsigned int u) { return __uint_as_float(u << 16); }
__device__ inline float hi16(unsigned int u) { return __uint_as_float(u & 0xFFFF0000u); }

// ---------------- prep: weight convert+transpose (blocks 0..767) + LN1 (blocks 768+) ----
__global__ __launch_bounds__(256) void prep(fp qw, fp pw, fp f1w, fp f2w,
                                            fp x, fp g, fp b,
                                            unsigned short* __restrict__ wt,
                                            unsigned short* __restrict__ xn) {
    const int bid = blockIdx.x;
    if (bid < 768) {
        int e = bid * 256 + threadIdx.x;
        float v;
        if (e < 49152)       { int n = e >> 7,  k = e & 127;          v = qw[(size_t)k * 384 + n]; }
        else if (e < 65536)  { int i = e - 49152;  int n = i >> 7, k = i & 127; v = pw[(size_t)k * 128 + n]; }
        else if (e < 131072) { int i = e - 65536;  int n = i >> 7, k = i & 127; v = f1w[(size_t)k * 512 + n]; }
        else                 { int i = e - 131072; int n = i >> 9, k = i & 511; v = f2w[(size_t)k * 128 + n]; }
        wt[e] = bf1(v);
    } else {
        const int t = threadIdx.x;
        const int row = (bid - 768) * 8 + (t >> 5);
        const int l = t & 31;
        const float4 v = *(const float4*)(x + (size_t)row * CDIM + l * 4);
        float s = v.x + v.y + v.z + v.w;
        float q = v.x * v.x + v.y * v.y + v.z * v.z + v.w * v.w;
#pragma unroll
        for (int m = 16; m >= 1; m >>= 1) { s += __shfl_xor(s, m); q += __shfl_xor(q, m); }
        float mu = s * (1.f / 128.f);
        float rs = rsqrtf(q * (1.f / 128.f) - mu * mu + LEPS);
        const float4 gv = *(const float4*)(g + l * 4);
        const float4 bv = *(const float4*)(b + l * 4);
        float a0 = (v.x - mu) * rs * gv.x + bv.x, a1 = (v.y - mu) * rs * gv.y + bv.y;
        float a2 = (v.z - mu) * rs * gv.z + bv.z, a3 = (v.w - mu) * rs * gv.w + bv.w;
        uint2 o; o.x = bfp2(a0, a1); o.y = bfp2(a2, a3);
        *(uint2*)(xn + (size_t)row * CDIM + l * 4) = o;
    }
}

// ================= MFMA GEMM kernels =================
// k1/k4/k5 tile: 128(M) x 64(N), 256 threads = 4 waves; wave = 32 rows (2 m-frags) x 4 n-tiles.

// ---------------- k1: QKV GEMM (A=xn, K=128, N=384); Q->f32, K/V->bf16 ----------------
__global__ __launch_bounds__(256) void k1_mfma(bfp16 xn, bfp16 wt0, fp wb,
                                               float* __restrict__ qb,
                                               unsigned short* __restrict__ kvb) {
    __shared__ unsigned int lds[12288];
    const int m0 = blockIdx.x * 128;
    const int nb = blockIdx.y * 64;
    const int tid = threadIdx.x;
#pragma unroll
    for (int i = 0; i < 8; i++) {
        int slot = tid + i * 256;
        int m = slot >> 4, c16 = slot & 15;
        const uint4 v4 = *(const uint4*)(xn + (size_t)(m0 + m) * CDIM + c16 * 8);
        *(uint4*)&lds[m * 64 + (c16 ^ (m & 15)) * 4] = v4;
    }
#pragma unroll
    for (int i = 0; i < 4; i++) {
        int slot = tid + i * 256;
        int n = slot >> 4, c16 = slot & 15;
        const uint4 v4 = *(const uint4*)(wt0 + (size_t)(nb + n) * 128 + c16 * 8);
        *(uint4*)&lds[8192 + n * 64 + (c16 ^ (n & 15)) * 4] = v4;
    }
    __syncthreads();

    const int lane = tid & 63, wid = tid >> 6, quad = lane >> 4, l16 = lane & 15;
    f32x4 acc[2][4];
#pragma unroll
    for (int mt = 0; mt < 2; mt++)
#pragma unroll
        for (int nt = 0; nt < 4; nt++) acc[mt][nt] = (f32x4){0.f, 0.f, 0.f, 0.f};
#pragma unroll
    for (int kk = 0; kk < 4; kk++) {
        int c = kk * 4 + quad;
        bf16x8 a0 = *(bf16x8*)&lds[(wid * 32 + l16) * 64 + (c ^ l16) * 4];
        bf16x8 a1 = *(bf16x8*)&lds[(wid * 32 + 16 + l16) * 64 + (c ^ l16) * 4];
#pragma unroll
        for (int nt = 0; nt < 4; nt++) {
            bf16x8 bf = *(bf16x8*)&lds[8192 + (nt * 16 + l16) * 64 + (c ^ l16) * 4];
            acc[0][nt] = __builtin_amdgcn_mfma_f32_16x16x32_bf16(a0, bf, acc[0][nt], 0, 0, 0);
            acc[1][nt] = __builtin_amdgcn_mfma_f32_16x16x32_bf16(a1, bf, acc[1][nt], 0, 0, 0);
        }
    }
#pragma unroll
    for (int nt = 0; nt < 4; nt++) {
        int col = nb + nt * 16 + l16;
        float bias = wb[col];
#pragma unroll
        for (int mt = 0; mt < 2; mt++)
#pragma unroll
            for (int r = 0; r < 4; r++) {
                int row = m0 + wid * 32 + mt * 16 + quad * 4 + r;
                float vres = acc[mt][nt][r] + bias;
                if (col < 128)
                    qb[(size_t)row * 128 + col] = vres * QSCALE;
                else if (col < 256)
                    kvb[(size_t)row * 256 + (col - 128)] = bf1(vres);
                else
                    kvb[(size_t)row * 256 + 128 + (col - 256)] = bf1(vres);
            }
    }
}

// ---------------- k2: neighborhood attention, 16 lanes per (token, head) ----------------
__global__ __launch_bounds__(256) void k2_attn(const float* __restrict__ qb,
                                               const unsigned short* __restrict__ kvb,
                                               fp rpb, unsigned short* __restrict__ attnb) {
    const int gid = blockIdx.x * 256 + threadIdx.x;   // 1048576
    const int d = gid & 3;
    const int g = (gid >> 2) & 3;
    const int head = (gid >> 4) & 3;
    const int token = gid >> 6;
    const int bb = token >> 12;
    const int y = (token >> 6) & 63;
    const int xx = token & 63;
    const int sy = min(max(y - 3, 0), 57);
    const int sx = min(max(xx - 3, 0), 57);

    const int koff = head * HD + d * 8;
    float q[8];
    {
        const float4* qp = (const float4*)(qb + (size_t)token * 128 + koff);
        float4 q0 = qp[0], q1 = qp[1];
        q[0] = q0.x; q[1] = q0.y; q[2] = q0.z; q[3] = q0.w;
        q[4] = q1.x; q[5] = q1.y; q[6] = q1.z; q[7] = q1.w;
    }

    const float* rp = rpb + head * 169 + (sy - y + 6) * 13 + (sx - xx + 6);
    const int nbase = (bb << 12) + sy * 64 + sx;

    float sc[13];
#pragma unroll
    for (int i = 0; i < 13; i++) {
        int n = g * 13 + i;
        bool ok = n < 49;
        int nn = ok ? n : 48;
        int dy = nn / 7, dx = nn - dy * 7;
        const uint4 kk = *(const uint4*)(kvb + (size_t)(nbase + dy * 64 + dx) * 256 + koff);
        float s = q[0] * lo16(kk.x) + q[1] * hi16(kk.x)
                + q[2] * lo16(kk.y) + q[3] * hi16(kk.y)
                + q[4] * lo16(kk.z) + q[5] * hi16(kk.z)
                + q[6] * lo16(kk.w) + q[7] * hi16(kk.w);
        s += __shfl_xor(s, 1);
        s += __shfl_xor(s, 2);
        sc[i] = ok ? (s + rp[dy * 13 + dx]) : -1e30f;
    }
    float mx = sc[0];
#pragma unroll
    for (int l = 1; l < 13; l++) mx = fmaxf(mx, sc[l]);
    mx = fmaxf(mx, __shfl_xor(mx, 4));
    mx = fmaxf(mx, __shfl_xor(mx, 8));
    float sum = 0.f;
#pragma unroll
    for (int l = 0; l < 13; l++) { sc[l] = __expf(sc[l] - mx); sum += sc[l]; }
    sum += __shfl_xor(sum, 4);
    sum += __shfl_xor(sum, 8);
    float inv = 1.f / sum;

    float o[8];
#pragma unroll
    for (int i = 0; i < 8; i++) o[i] = 0.f;
#pragma unroll
    for (int i = 0; i < 13; i++) {
        int n = g * 13 + i;
        int nn = (n < 49) ? n : 48;
        int dy = nn / 7, dx = nn - dy * 7;
        float p = sc[i] * inv;
        const uint4 vv = *(const uint4*)(kvb + (size_t)(nbase + dy * 64 + dx) * 256 + 128 + koff);
        o[0] += p * lo16(vv.x); o[1] += p * hi16(vv.x);
        o[2] += p * lo16(vv.y); o[3] += p * hi16(vv.y);
        o[4] += p * lo16(vv.z); o[5] += p * hi16(vv.z);
        o[6] += p * lo16(vv.w); o[7] += p * hi16(vv.w);
    }
#pragma unroll
    for (int i = 0; i < 8; i++) {
        o[i] += __shfl_xor(o[i], 4);
        o[i] += __shfl_xor(o[i], 8);
    }
    if (g == 0) {
        uint4 ov;
        ov.x = bfp2(o[0], o[1]); ov.y = bfp2(o[2], o[3]);
        ov.z = bfp2(o[4], o[5]); ov.w = bfp2(o[6], o[7]);
        *(uint4*)(attnb + (size_t)token * 128 + koff) = ov;
    }
}

// ---------------- k3: proj GEMM (64x128 tile) + residual + fused LN2 -> h, hn ----------
__global__ __launch_bounds__(256) void k3_mfma(bfp16 attnb, fp x, bfp16 wt1, fp pb,
                                               fp g2, fp b2,
                                               float* __restrict__ h,
                                               unsigned short* __restrict__ hn) {
    __shared__ unsigned int lds[12288];   // A 4096 + B 8192
    const int m0 = blockIdx.x * 64;
    const int tid = threadIdx.x;
#pragma unroll
    for (int i = 0; i < 4; i++) {
        int slot = tid + i * 256;
        int m = slot >> 4, c16 = slot & 15;
        const uint4 v4 = *(const uint4*)(attnb + (size_t)(m0 + m) * CDIM + c16 * 8);
        *(uint4*)&lds[m * 64 + (c16 ^ (m & 15)) * 4] = v4;
    }
#pragma unroll
    for (int i = 0; i < 8; i++) {
        int slot = tid + i * 256;
        int n = slot >> 4, c16 = slot & 15;
        const uint4 v4 = *(const uint4*)(wt1 + (size_t)n * 128 + c16 * 8);
        *(uint4*)&lds[4096 + n * 64 + (c16 ^ (n & 15)) * 4] = v4;
    }
    __syncthreads();

    const int lane = tid & 63, wid = tid >> 6, quad = lane >> 4, l16 = lane & 15;
    const int mrow = wid * 16 + l16;
    f32x4 acc[8];
#pragma unroll
    for (int nt = 0; nt < 8; nt++) acc[nt] = (f32x4){0.f, 0.f, 0.f, 0.f};
#pragma unroll
    for (int kk = 0; kk < 4; kk++) {
        int c = kk * 4 + quad;
        bf16x8 a = *(bf16x8*)&lds[mrow * 64 + (c ^ l16) * 4];
#pragma unroll
        for (int nt = 0; nt < 8; nt++) {
            bf16x8 bf = *(bf16x8*)&lds[4096 + (nt * 16 + l16) * 64 + (c ^ l16) * 4];
            acc[nt] = __builtin_amdgcn_mfma_f32_16x16x32_bf16(a, bf, acc[nt], 0, 0, 0);
        }
    }
    float s[4] = {0.f, 0.f, 0.f, 0.f}, q[4] = {0.f, 0.f, 0.f, 0.f};
#pragma unroll
    for (int nt = 0; nt < 8; nt++) {
        int col = nt * 16 + l16;
        float bias = pb[col];
#pragma unroll
        for (int r = 0; r < 4; r++) {
            int row = m0 + wid * 16 + quad * 4 + r;
            float hv = x[(size_t)row * CDIM + col] + acc[nt][r] + bias;
            h[(size_t)row * CDIM + col] = hv;
            acc[nt][r] = hv;
            s[r] += hv; q[r] += hv * hv;
        }
    }
#pragma unroll
    for (int m = 1; m <= 8; m <<= 1) {
#pragma unroll
        for (int r = 0; r < 4; r++) {
            s[r] += __shfl_xor(s[r], m);
            q[r] += __shfl_xor(q[r], m);
        }
    }
    float mu[4], rs[4];
#pragma unroll
    for (int r = 0; r < 4; r++) {
        mu[r] = s[r] * (1.f / 128.f);
        rs[r] = rsqrtf(q[r] * (1.f / 128.f) - mu[r] * mu[r] + LEPS);
    }
#pragma unroll
    for (int nt = 0; nt < 8; nt++) {
        int col = nt * 16 + l16;
        float gg = g2[col], bb = b2[col];
#pragma unroll
        for (int r = 0; r < 4; r++) {
            int row = m0 + wid * 16 + quad * 4 + r;
            hn[(size_t)row * CDIM + col] = bf1((acc[nt][r] - mu[r]) * rs[r] * gg + bb);
        }
    }
}

// ---------------- k4: fc1 + GELU (A=hn, K=128, N=512) -> y1 bf16 ----------------
__global__ __launch_bounds__(256) void k4_mfma(bfp16 hn, bfp16 wt2, fp wb,
                                               unsigned short* __restrict__ y1) {
    __shared__ unsigned int lds[12288];
    const int m0 = blockIdx.x * 128;
    const int nb = blockIdx.y * 64;
    const int tid = threadIdx.x;
#pragma unroll
    for (int i = 0; i < 8; i++) {
        int slot = tid + i * 256;
        int m = slot >> 4, c16 = slot & 15;
        const uint4 v4 = *(const uint4*)(hn + (size_t)(m0 + m) * CDIM + c16 * 8);
        *(uint4*)&lds[m * 64 + (c16 ^ (m & 15)) * 4] = v4;
    }
#pragma unroll
    for (int i = 0; i < 4; i++) {
        int slot = tid + i * 256;
        int n = slot >> 4, c16 = slot & 15;
        const uint4 v4 = *(const uint4*)(wt2 + (size_t)(nb + n) * 128 + c16 * 8);
        *(uint4*)&lds[8192 + n * 64 + (c16 ^ (n & 15)) * 4] = v4;
    }
    __syncthreads();

    const int lane = tid & 63, wid = tid >> 6, quad = lane >> 4, l16 = lane & 15;
    f32x4 acc[2][4];
#pragma unroll
    for (int mt = 0; mt < 2; mt++)
#pragma unroll
        for (int nt = 0; nt < 4; nt++) acc[mt][nt] = (f32x4){0.f, 0.f, 0.f, 0.f};
#pragma unroll
    for (int kk = 0; kk < 4; kk++) {
        int c = kk * 4 + quad;
        bf16x8 a0 = *(bf16x8*)&lds[(wid * 32 + l16) * 64 + (c ^ l16) * 4];
        bf16x8 a1 = *(bf16x8*)&lds[(wid * 32 + 16 + l16) * 64 + (c ^ l16) * 4];
#pragma unroll
        for (int nt = 0; nt < 4; nt++) {
            bf16x8 bf = *(bf16x8*)&lds[8192 + (nt * 16 + l16) * 64 + (c ^ l16) * 4];
            acc[0][nt] = __builtin_amdgcn_mfma_f32_16x16x32_bf16(a0, bf, acc[0][nt], 0, 0, 0);
            acc[1][nt] = __builtin_amdgcn_mfma_f32_16x16x32_bf16(a1, bf, acc[1][nt], 0, 0, 0);
        }
    }
#pragma unroll
    for (int nt = 0; nt < 4; nt++) {
        int col = nb + nt * 16 + l16;
        float bias = wb[col];
#pragma unroll
        for (int mt = 0; mt < 2; mt++)
#pragma unroll
            for (int r = 0; r < 4; r++) {
                int row = m0 + wid * 32 + mt * 16 + quad * 4 + r;
                float z = acc[mt][nt][r] + bias;
                y1[(size_t)row * HID + col] = bf1(0.5f * z * (1.f + erff(z * 0.70710678118654752f)));
            }
    }
}

// ---------------- k5: fc2 + residual (K=512 in 4 chunks, N=128) ----------------
__global__ __launch_bounds__(256) void k5_mfma(bfp16 y1, fp h, bfp16 wt3, fp wb,
                                               float* __restrict__ out) {
    __shared__ unsigned int lds[12288];
    const int m0 = blockIdx.x * 128;
    const int nb = blockIdx.y * 64;
    const int tid = threadIdx.x;
    const int lane = tid & 63, wid = tid >> 6, quad = lane >> 4, l16 = lane & 15;
    f32x4 acc[2][4];
#pragma unroll
    for (int mt = 0; mt < 2; mt++)
#pragma unroll
        for (int nt = 0; nt < 4; nt++) acc[mt][nt] = (f32x4){0.f, 0.f, 0.f, 0.f};

    for (int kc = 0; kc < 4; kc++) {
        if (kc) __syncthreads();
#pragma unroll
        for (int i = 0; i < 8; i++) {
            int slot = tid + i * 256;
            int m = slot >> 4, c16 = slot & 15;
            const uint4 v4 = *(const uint4*)(y1 + (size_t)(m0 + m) * HID + kc * 128 + c16 * 8);
            *(uint4*)&lds[m * 64 + (c16 ^ (m & 15)) * 4] = v4;
        }
#pragma unroll
        for (int i = 0; i < 4; i++) {
            int slot = tid + i * 256;
            int n = slot >> 4, c16 = slot & 15;
            const uint4 v4 = *(const uint4*)(wt3 + (size_t)(nb + n) * 512 + kc * 128 + c16 * 8);
            *(uint4*)&lds[8192 + n * 64 + (c16 ^ (n & 15)) * 4] = v4;
        }
        __syncthreads();
#pragma unroll
        for (int kk = 0; kk < 4; kk++) {
            int c = kk * 4 + quad;
            bf16x8 a0 = *(bf16x8*)&lds[(wid * 32 + l16) * 64 + (c ^ l16) * 4];
            bf16x8 a1 = *(bf16x8*)&lds[(wid * 32 + 16 + l16) * 64 + (c ^ l16) * 4];
#pragma unroll
            for (int nt = 0; nt < 4; nt++) {
                bf16x8 bf = *(bf16x8*)&lds[8192 + (nt * 16 + l16) * 64 + (c ^ l16) * 4];
                acc[0][nt] = __builtin_amdgcn_mfma_f32_16x16x32_bf16(a0, bf, acc[0][nt], 0, 0, 0);
                acc[1][nt] = __builtin_amdgcn_mfma_f32_16x16x32_bf16(a1, bf, acc[1][nt], 0, 0, 0);
            }
        }
    }
#pragma unroll
    for (int nt = 0; nt < 4; nt++) {
        int col = nb + nt * 16 + l16;
        float bias = wb[col];
#pragma unroll
        for (int mt = 0; mt < 2; mt++)
#pragma unroll
            for (int r = 0; r < 4; r++) {
                int row = m0 + wid * 32 + mt * 16 + quad * 4 + r;
                out[(size_t)row * CDIM + col] = h[(size_t)row * CDIM + col] + acc[mt][nt][r] + bias;
            }
    }
}

extern "C" void kernel_launch(void* const* d_in, const int* in_sizes, int n_in,
                              void* d_out, int out_size, void* d_ws, size_t ws_size,
                              hipStream_t stream) {
    fp x      = (fp)d_in[0];
    fp ln1_g  = (fp)d_in[1];
    fp ln1_b  = (fp)d_in[2];
    fp qkv_w  = (fp)d_in[3];
    fp qkv_b  = (fp)d_in[4];
    fp rpb    = (fp)d_in[5];
    fp proj_w = (fp)d_in[6];
    fp proj_b = (fp)d_in[7];
    fp ln2_g  = (fp)d_in[8];
    fp ln2_b  = (fp)d_in[9];
    fp fc1_w  = (fp)d_in[10];
    fp fc1_b  = (fp)d_in[11];
    fp fc2_w  = (fp)d_in[12];
    fp fc2_b  = (fp)d_in[13];
    float* out = (float*)d_out;

    float* ws = (float*)d_ws;
    float* h  = ws;
    unsigned short* xn = (unsigned short*)(h + (size_t)TOKS * CDIM);
    unsigned short* hn = xn + (size_t)TOKS * CDIM;
    float* qb = (float*)(hn + (size_t)TOKS * CDIM);
    unsigned short* kvb   = (unsigned short*)(qb + (size_t)TOKS * CDIM);
    unsigned short* attnb = kvb + (size_t)TOKS * 256;
    unsigned short* wt    = attnb + (size_t)TOKS * CDIM;
    unsigned short* y1    = (unsigned short*)qb;   // aliases qb+kvb (dead by k4)

    unsigned short* wt0 = wt;            // qkv  [384][128]
    unsigned short* wt1 = wt + 49152;    // proj [128][128]
    unsigned short* wt2 = wt + 65536;    // fc1  [512][128]
    unsigned short* wt3 = wt + 131072;   // fc2  [128][512]

    prep<<<768 + TOKS / 8, 256, 0, stream>>>(qkv_w, proj_w, fc1_w, fc2_w, x, ln1_g, ln1_b, wt, xn);
    k1_mfma<<<dim3(TOKS / 128, 6), 256, 0, stream>>>(xn, wt0, qkv_b, qb, kvb);
    k2_attn<<<TOKS * NH * 16 / 256, 256, 0, stream>>>(qb, kvb, rpb, attnb);
    k3_mfma<<<TOKS / 64, 256, 0, stream>>>(attnb, x, wt1, proj_b, ln2_g, ln2_b, h, hn);
    k4_mfma<<<dim3(TOKS / 128, 8), 256, 0, stream>>>(hn, wt2, fc1_b, y1);
    k5_mfma<<<dim3(TOKS / 128, 2), 256, 0, stream>>>(y1, h, wt3, fc2_b, out);
}